// Round 7
// baseline (399.456 us; speedup 1.0000x reference)
//
#include <hip/hip_runtime.h>

// 2-layer LSTM (B=2048,T=512,in=4,H=64) + FC + tanh. MFMA f16, wave-specialized,
// TWO-SEGMENT rounds with gates held in REGISTERS across the barrier.
//
// Grid 256 x 512 threads. Waves 0-3 = L0 group, waves 4-7 = L1 group (one of
// each per SIMD). Wave wl owns N-tiles {wl,wl+4,wl+8,wl+12} = all 4 gates of
// its 16 units -> MFMA C/D has i,f,g,o of a cell in the same lane; gates stay
// in VGPRs from MFMA (one segment) to act (next segment) -- no LDS exchange.
//
// Round r:  Seg A: L0-MFMA(r) [h0(r-1)@pv]      | L1-act(r-2) -> h1(r-2)
//           Seg B: L0-act(r) -> h0(r)@pr        | L1-MFMA(r-1) [h0(r-1)@pv,
//                                                 h1(r-2) written in Seg A]
// Each segment pairs one group's MFMA with the other group's VALU/trans ->
// cross-pipe overlap instead of the 1-barrier phase-lock (R6's limiter).
// h1 single-buffered (all uses barrier-separated); h0 parity-dbuf.
// Rounds 0,1,512,513 peeled: hot loop has no keep-mask, no bounds branch,
// and parity-constant LDS addresses (pairs of rounds per iteration).

#define HID 64
#define TSTEPS 512
#define MB 8
#define BLK 512
#define HSTR 72   // f16 words per h row (144 B: 16B-aligned b128, bank-spread)
#define LOG2E  1.4426950408889634f
#define LOG2E2 2.8853900817779268f

typedef _Float16 f16;
typedef _Float16 half8 __attribute__((ext_vector_type(8)));
typedef _Float16 half4 __attribute__((ext_vector_type(4)));
typedef float f32x4 __attribute__((ext_vector_type(4)));

__device__ __forceinline__ float sig2(float y) {   // sigmoid(x), y = x*log2e
    return __builtin_amdgcn_rcpf(1.0f + __builtin_amdgcn_exp2f(-y));
}
__device__ __forceinline__ float tanh2(float y) {  // tanh(x), y = x*2*log2e
    return fmaf(2.0f, __builtin_amdgcn_rcpf(1.0f + __builtin_amdgcn_exp2f(-y)), -1.0f);
}

__global__ __launch_bounds__(BLK, 2) void lstm_mfma(
    const float* __restrict__ x,      // (2048, 512, 4)
    const float* __restrict__ w_ih0,  // (256, 4)
    const float* __restrict__ w_hh0,  // (256, 64)
    const float* __restrict__ b_ih0,  // (256,)
    const float* __restrict__ b_hh0,  // (256,)
    const float* __restrict__ w_ih1,  // (256, 64)
    const float* __restrict__ w_hh1,  // (256, 64)
    const float* __restrict__ b_ih1,  // (256,)
    const float* __restrict__ b_hh1,  // (256,)
    const float* __restrict__ fc_w,   // (64, 64)
    const float* __restrict__ fc_b,   // (64,)
    float* __restrict__ out)          // (2048, 64)
{
    __shared__ f16 xs[TSTEPS * MB * 4];     // 32 KB
    __shared__ f16 h0s[2][MB * HSTR];       // parity dbuf
    __shared__ f16 h1s[MB * HSTR];          // single buffer

    const int tid  = threadIdx.x;
    const int w    = tid >> 6;        // wave 0..7
    const int l    = tid & 63;
    const int quad = l >> 4;
    const int l15  = l & 15;
    const int wl   = w & 3;
    const bool isL0 = (w < 4);
    const int b0   = blockIdx.x * MB;

    // ---- stage x into LDS as f16 ----
    for (int it = tid; it < MB * TSTEPS; it += BLK) {
        const int m = it >> 9;
        const int t = it & 511;
        const float4 v = *((const float4*)x + (size_t)(b0 + m) * TSTEPS + t);
        *(half4*)(xs + (t * MB + m) * 4) =
            (half4){ (f16)v.x, (f16)v.y, (f16)v.z, (f16)v.w };
    }
    for (int it = tid; it < MB * HSTR; it += BLK) {
        h0s[0][it] = (f16)0.f; h0s[1][it] = (f16)0.f; h1s[it] = (f16)0.f;
    }

    // ---- B-fragments: 4 N-tiles x up-to-4 K-chunks, prescaled by log2e ----
    // B[k=quad*8+j][n=(wl+4*ti)*16+l15]; tile ti == gate ti of units wl*16+l15.
    // L0: [0]=x-proj(pad), [1-2]=w_hh0, [3]=Z.  L1: [0-1]=w_ih1, [2-3]=w_hh1.
    half8 Bf[4][4];
    float biasr[4];
    const half8 Z = { (f16)0.f,(f16)0.f,(f16)0.f,(f16)0.f,
                      (f16)0.f,(f16)0.f,(f16)0.f,(f16)0.f };
    #pragma unroll
    for (int ti = 0; ti < 4; ++ti) {
        const int n = (wl + 4 * ti) * 16 + l15;
        const float sc = (ti == 2) ? LOG2E2 : LOG2E;   // g-gate feeds tanh2
        if (isL0) {
            biasr[ti] = (b_ih0[n] + b_hh0[n]) * sc;
            half8 pz = Z;
            if (quad == 0) {
                const float4 v = *(const float4*)(w_ih0 + n * 4);
                pz[0] = (f16)(v.x * sc); pz[1] = (f16)(v.y * sc);
                pz[2] = (f16)(v.z * sc); pz[3] = (f16)(v.w * sc);
            }
            Bf[ti][0] = pz;
            #pragma unroll
            for (int ks = 0; ks < 2; ++ks) {
                const int ko = ks * 32 + quad * 8;
                const float4 a = *(const float4*)(w_hh0 + n * HID + ko);
                const float4 b = *(const float4*)(w_hh0 + n * HID + ko + 4);
                Bf[ti][1 + ks] = (half8){
                    (f16)(a.x*sc),(f16)(a.y*sc),(f16)(a.z*sc),(f16)(a.w*sc),
                    (f16)(b.x*sc),(f16)(b.y*sc),(f16)(b.z*sc),(f16)(b.w*sc) };
            }
            Bf[ti][3] = Z;
        } else {
            biasr[ti] = (b_ih1[n] + b_hh1[n]) * sc;
            #pragma unroll
            for (int ks = 0; ks < 2; ++ks) {
                const int ko = ks * 32 + quad * 8;
                const float4 a = *(const float4*)(w_ih1 + n * HID + ko);
                const float4 b = *(const float4*)(w_ih1 + n * HID + ko + 4);
                Bf[ti][ks] = (half8){
                    (f16)(a.x*sc),(f16)(a.y*sc),(f16)(a.z*sc),(f16)(a.w*sc),
                    (f16)(b.x*sc),(f16)(b.y*sc),(f16)(b.z*sc),(f16)(b.w*sc) };
                const float4 c = *(const float4*)(w_hh1 + n * HID + ko);
                const float4 d = *(const float4*)(w_hh1 + n * HID + ko + 4);
                Bf[ti][2 + ks] = (half8){
                    (f16)(c.x*sc),(f16)(c.y*sc),(f16)(c.z*sc),(f16)(c.w*sc),
                    (f16)(d.x*sc),(f16)(d.y*sc),(f16)(d.z*sc),(f16)(d.w*sc) };
            }
        }
    }

    // cell ownership: quads 0-1 own regs {0,1}, quads 2-3 own regs {2,3};
    // batch row = (quad&1)*4 + base + j, unit = wl*16 + l15.
    const bool lo   = (quad < 2);
    const int  mrow = (quad & 1) * 4 + (lo ? 0 : 2);
    const int  uu   = wl * 16 + l15;
    const int  hb   = (l15 & 7) * HSTR + quad * 8;   // A-frag base (rows dup x2)
    float cst0 = 0.f, cst1 = 0.f;
    f32x4 g[4];                                      // gates live across barriers

    auto l0_mfma = [&](int r, const f16* h0rd) {
        const half4 xv = *(const half4*)(xs + (r * MB + (l15 & 7)) * 4);
        half8 ax = Z;
        if (quad == 0) { ax[0]=xv[0]; ax[1]=xv[1]; ax[2]=xv[2]; ax[3]=xv[3]; }
        const half8 A1 = *(const half8*)(h0rd + hb);
        const half8 A2 = *(const half8*)(h0rd + hb + 32);
        #pragma unroll
        for (int ti = 0; ti < 4; ++ti) {
            f32x4 acc = { biasr[ti], biasr[ti], biasr[ti], biasr[ti] };
            acc   = __builtin_amdgcn_mfma_f32_16x16x32_f16(ax, Bf[ti][0], acc, 0, 0, 0);
            acc   = __builtin_amdgcn_mfma_f32_16x16x32_f16(A1, Bf[ti][1], acc, 0, 0, 0);
            g[ti] = __builtin_amdgcn_mfma_f32_16x16x32_f16(A2, Bf[ti][2], acc, 0, 0, 0);
        }
    };
    auto l1_mfma = [&](const f16* h0rd) {
        const half8 A1 = *(const half8*)(h0rd + hb);
        const half8 A2 = *(const half8*)(h0rd + hb + 32);
        const half8 A3 = *(const half8*)(h1s + hb);
        const half8 A4 = *(const half8*)(h1s + hb + 32);
        #pragma unroll
        for (int ti = 0; ti < 4; ++ti) {
            f32x4 acc = { biasr[ti], biasr[ti], biasr[ti], biasr[ti] };
            acc   = __builtin_amdgcn_mfma_f32_16x16x32_f16(A1, Bf[ti][0], acc, 0, 0, 0);
            acc   = __builtin_amdgcn_mfma_f32_16x16x32_f16(A2, Bf[ti][1], acc, 0, 0, 0);
            acc   = __builtin_amdgcn_mfma_f32_16x16x32_f16(A3, Bf[ti][2], acc, 0, 0, 0);
            g[ti] = __builtin_amdgcn_mfma_f32_16x16x32_f16(A4, Bf[ti][3], acc, 0, 0, 0);
        }
    };
    auto act_store = [&](f16* dst) {
        #pragma unroll
        for (int j = 0; j < 2; ++j) {
            const float pi = lo ? g[0][j] : g[0][2 + j];
            const float pf = lo ? g[1][j] : g[1][2 + j];
            const float pg = lo ? g[2][j] : g[2][2 + j];
            const float po = lo ? g[3][j] : g[3][2 + j];
            float& c = j ? cst1 : cst0;
            c = sig2(pf) * c + sig2(pi) * tanh2(pg);
            dst[(mrow + j) * HSTR + uu] = (f16)(sig2(po) * tanh2(c * LOG2E2));
        }
    };

    __syncthreads();

    // ---- round 0 (L1 idle; h0(-1) = zeros) ----
    if (isL0) l0_mfma(0, h0s[1]);
    __syncthreads();
    if (isL0) act_store(h0s[0]);                 // h0(0)
    __syncthreads();
    // ---- round 1 (L1 starts MFMA(0): h0(0), h1(-1)=zeros) ----
    if (isL0) l0_mfma(1, h0s[0]);
    __syncthreads();
    if (isL0) act_store(h0s[1]);                 // h0(1)
    else      l1_mfma(h0s[0]);                   // gates(0)
    __syncthreads();

    // ---- main rounds 2..511, parity pairs ----
    #pragma unroll 1
    for (int r = 2; r < TSTEPS; r += 2) {
        // round r (even: pr=0, pv=1)
        if (isL0) l0_mfma(r, h0s[1]);            // MFMA(r)
        else      act_store(h1s);                // h1(r-2)
        __syncthreads();
        if (isL0) act_store(h0s[0]);             // h0(r)
        else      l1_mfma(h0s[1]);               // gates(r-1)
        __syncthreads();
        // round r+1 (odd: pr=1, pv=0)
        if (isL0) l0_mfma(r + 1, h0s[0]);        // MFMA(r+1)
        else      act_store(h1s);                // h1(r-1)
        __syncthreads();
        if (isL0) act_store(h0s[1]);             // h0(r+1)
        else      l1_mfma(h0s[0]);               // gates(r)
        __syncthreads();
    }

    // ---- drain: rounds 512, 513 (L0 idle) ----
    if (!isL0) act_store(h1s);                   // h1(510)
    __syncthreads();
    if (!isL0) l1_mfma(h0s[1]);                  // gates(511), h0(511)@1
    __syncthreads();
    if (!isL0) act_store(h1s);                   // h1(511)
    __syncthreads();

    // ---- epilogue: out[b][v] = tanh(h1(511) . fc_w[v] + fc_b[v]) ----
    {
        const int v = tid & 63;
        const int m = tid >> 6;
        float a = fc_b[v];
        const f16* hp = h1s + m * HSTR;
        const float4* wp = (const float4*)(fc_w + v * HID);
        #pragma unroll
        for (int kk = 0; kk < HID / 4; ++kk) {
            const float4 wv = wp[kk];
            a += (float)hp[kk * 4 + 0] * wv.x + (float)hp[kk * 4 + 1] * wv.y
               + (float)hp[kk * 4 + 2] * wv.z + (float)hp[kk * 4 + 3] * wv.w;
        }
        out[(size_t)(b0 + m) * HID + v] = tanh2(a * LOG2E2);
    }
}

extern "C" void kernel_launch(void* const* d_in, const int* in_sizes, int n_in,
                              void* d_out, int out_size, void* d_ws, size_t ws_size,
                              hipStream_t stream) {
    const float* x     = (const float*)d_in[0];
    const float* w_ih0 = (const float*)d_in[1];
    const float* w_hh0 = (const float*)d_in[2];
    const float* b_ih0 = (const float*)d_in[3];
    const float* b_hh0 = (const float*)d_in[4];
    const float* w_ih1 = (const float*)d_in[5];
    const float* w_hh1 = (const float*)d_in[6];
    const float* b_ih1 = (const float*)d_in[7];
    const float* b_hh1 = (const float*)d_in[8];
    const float* fc_w  = (const float*)d_in[9];
    const float* fc_b  = (const float*)d_in[10];
    float* out = (float*)d_out;

    const int B = in_sizes[0] / (TSTEPS * 4);   // 2048
    lstm_mfma<<<dim3(B / MB), dim3(BLK), 0, stream>>>(
        x, w_ih0, w_hh0, b_ih0, b_hh0, w_ih1, w_hh1, b_ih1, b_hh1, fc_w, fc_b, out);
}

// Round 8
// 332.515 us; speedup vs baseline: 1.2013x; 1.2013x over previous
//
#include <hip/hip_runtime.h>

// 2-layer LSTM (B=2048,T=512,in=4,H=64) + FC + tanh. MFMA f16, wave-specialized,
// 1 barrier/round (R6 schedule — empirically fastest), VALU-issue minimized.
//
// Additive-issue model (validated R3/R6/R7): per-SIMD round time =
// MFMA-pipe-cycles + VALU-issue-cycles + barrier. MFMA is structural
// (28/SIMD/round); this round cuts VALU:
//  - bias lives in persistent f32x4 regs used directly as MFMA C operand
//    (kills 16 v_mov/wave/round of bias splat)
//  - A-rows 8-15 carry ROTATED batches {2,3,0,1,6,7,4,5} so every quad's act
//    cells are C/D regs {0,1} -> no runtime reg-index cndmasks in act
//  - rounds 0/512 peeled -> hot loop has no keep-mask / bounds branch; 2-round
//    unroll makes LDS parity addresses compile-time.
//
// Round r: L0 waves (0-3): MFMA step r [x(r), h0(r-1)@pv] -> act -> h0(r)@pr
//          L1 waves (4-7): MFMA step r-1 [h0(r-1)@pv, h1(r-2)@pr] -> act -> h1(r-1)@pv
//          one __syncthreads.

#define HID 64
#define TSTEPS 512
#define MB 8
#define BLK 512
#define HSTR 72   // f16 words per h row (144 B: 16B-aligned b128)
#define LOG2E  1.4426950408889634f
#define LOG2E2 2.8853900817779268f

typedef _Float16 f16;
typedef _Float16 half8 __attribute__((ext_vector_type(8)));
typedef _Float16 half4 __attribute__((ext_vector_type(4)));
typedef float f32x4 __attribute__((ext_vector_type(4)));

__device__ __forceinline__ float sig2(float y) {   // sigmoid(x), y = x*log2e
    return __builtin_amdgcn_rcpf(1.0f + __builtin_amdgcn_exp2f(-y));
}
__device__ __forceinline__ float tanh2(float y) {  // tanh(x), y = x*2*log2e
    return fmaf(2.0f, __builtin_amdgcn_rcpf(1.0f + __builtin_amdgcn_exp2f(-y)), -1.0f);
}

__global__ __launch_bounds__(BLK, 2) void lstm_mfma(
    const float* __restrict__ x,      // (2048, 512, 4)
    const float* __restrict__ w_ih0,  // (256, 4)
    const float* __restrict__ w_hh0,  // (256, 64)
    const float* __restrict__ b_ih0,  // (256,)
    const float* __restrict__ b_hh0,  // (256,)
    const float* __restrict__ w_ih1,  // (256, 64)
    const float* __restrict__ w_hh1,  // (256, 64)
    const float* __restrict__ b_ih1,  // (256,)
    const float* __restrict__ b_hh1,  // (256,)
    const float* __restrict__ fc_w,   // (64, 64)
    const float* __restrict__ fc_b,   // (64,)
    float* __restrict__ out)          // (2048, 64)
{
    __shared__ f16 xs[TSTEPS * MB * 4];     // 32 KB
    __shared__ f16 h0s[2][MB * HSTR];       // parity dbuf
    __shared__ f16 h1s[2][MB * HSTR];       // parity dbuf

    const int tid  = threadIdx.x;
    const int w    = tid >> 6;        // wave 0..7
    const int l    = tid & 63;
    const int quad = l >> 4;
    const int l15  = l & 15;
    const int wl   = w & 3;
    const bool isL0 = (w < 4);
    const int b0   = blockIdx.x * MB;

    // rotated duplicate-row map: A-row m holds batch RM[m];
    // rows 0-7 = batches 0-7, rows 8-15 = batches {2,3,0,1,6,7,4,5}.
    const int RM = (l15 < 8) ? l15 : ((l15 & 4) | ((l15 + 2) & 3));

    // ---- stage x into LDS as f16 ----
    for (int it = tid; it < MB * TSTEPS; it += BLK) {
        const int m = it >> 9;
        const int t = it & 511;
        const float4 v = *((const float4*)x + (size_t)(b0 + m) * TSTEPS + t);
        *(half4*)(xs + (t * MB + m) * 4) =
            (half4){ (f16)v.x, (f16)v.y, (f16)v.z, (f16)v.w };
    }
    for (int it = tid; it < MB * HSTR; it += BLK) {
        h0s[0][it] = (f16)0.f; h0s[1][it] = (f16)0.f;
        h1s[0][it] = (f16)0.f; h1s[1][it] = (f16)0.f;
    }

    // ---- B-fragments: 4 N-tiles x up-to-4 K-chunks, prescaled by log2e ----
    // B[k=quad*8+j][n=(wl+4*ti)*16+l15]; tile ti == gate ti of units wl*16+l15.
    // L0: [0]=x-proj(pad), [1-2]=w_hh0.  L1: [0-1]=w_ih1, [2-3]=w_hh1.
    half8 Bf[4][4];
    f32x4 biasv[4];                 // persistent C-operand (no per-round splat)
    const half8 Z = { (f16)0.f,(f16)0.f,(f16)0.f,(f16)0.f,
                      (f16)0.f,(f16)0.f,(f16)0.f,(f16)0.f };
    #pragma unroll
    for (int ti = 0; ti < 4; ++ti) {
        const int n = (wl + 4 * ti) * 16 + l15;
        const float sc = (ti == 2) ? LOG2E2 : LOG2E;   // g-gate feeds tanh2
        float bval;
        if (isL0) {
            bval = (b_ih0[n] + b_hh0[n]) * sc;
            half8 pz = Z;
            if (quad == 0) {
                const float4 v = *(const float4*)(w_ih0 + n * 4);
                pz[0] = (f16)(v.x * sc); pz[1] = (f16)(v.y * sc);
                pz[2] = (f16)(v.z * sc); pz[3] = (f16)(v.w * sc);
            }
            Bf[ti][0] = pz;
            #pragma unroll
            for (int ks = 0; ks < 2; ++ks) {
                const int ko = ks * 32 + quad * 8;
                const float4 a = *(const float4*)(w_hh0 + n * HID + ko);
                const float4 b = *(const float4*)(w_hh0 + n * HID + ko + 4);
                Bf[ti][1 + ks] = (half8){
                    (f16)(a.x*sc),(f16)(a.y*sc),(f16)(a.z*sc),(f16)(a.w*sc),
                    (f16)(b.x*sc),(f16)(b.y*sc),(f16)(b.z*sc),(f16)(b.w*sc) };
            }
            Bf[ti][3] = Z;
        } else {
            bval = (b_ih1[n] + b_hh1[n]) * sc;
            #pragma unroll
            for (int ks = 0; ks < 2; ++ks) {
                const int ko = ks * 32 + quad * 8;
                const float4 a = *(const float4*)(w_ih1 + n * HID + ko);
                const float4 b = *(const float4*)(w_ih1 + n * HID + ko + 4);
                Bf[ti][ks] = (half8){
                    (f16)(a.x*sc),(f16)(a.y*sc),(f16)(a.z*sc),(f16)(a.w*sc),
                    (f16)(b.x*sc),(f16)(b.y*sc),(f16)(b.z*sc),(f16)(b.w*sc) };
                const float4 c = *(const float4*)(w_hh1 + n * HID + ko);
                const float4 d = *(const float4*)(w_hh1 + n * HID + ko + 4);
                Bf[ti][2 + ks] = (half8){
                    (f16)(c.x*sc),(f16)(c.y*sc),(f16)(c.z*sc),(f16)(c.w*sc),
                    (f16)(d.x*sc),(f16)(d.y*sc),(f16)(d.z*sc),(f16)(d.w*sc) };
            }
        }
        biasv[ti] = (f32x4){ bval, bval, bval, bval };
    }

    // act ownership (rotation makes reg index uniform): lane (quad,l15) owns
    // C/D regs {0,1} = batches {mrow, mrow+1}, unit uu.
    // quad 0,1,2,3 -> mrow 0,4,2,6.
    const int  mrow = (quad & 1) * 4 + (quad & 2);
    const int  uu   = wl * 16 + l15;
    const int  hb   = RM * HSTR + quad * 8;   // A-frag base (rotated rows)
    float cst0 = 0.f, cst1 = 0.f;
    f32x4 g[4];

    auto l0_mfma = [&](int r, const f16* h0rd) {
        const half4 xv = *(const half4*)(xs + (r * MB + RM) * 4);
        half8 ax = Z;
        if (quad == 0) { ax[0]=xv[0]; ax[1]=xv[1]; ax[2]=xv[2]; ax[3]=xv[3]; }
        const half8 A1 = *(const half8*)(h0rd + hb);
        const half8 A2 = *(const half8*)(h0rd + hb + 32);
        #pragma unroll
        for (int ti = 0; ti < 4; ++ti) {
            f32x4 acc;
            acc   = __builtin_amdgcn_mfma_f32_16x16x32_f16(ax, Bf[ti][0], biasv[ti], 0, 0, 0);
            acc   = __builtin_amdgcn_mfma_f32_16x16x32_f16(A1, Bf[ti][1], acc, 0, 0, 0);
            g[ti] = __builtin_amdgcn_mfma_f32_16x16x32_f16(A2, Bf[ti][2], acc, 0, 0, 0);
        }
    };
    auto l1_mfma = [&](const f16* h0rd, const f16* h1rd) {
        const half8 A1 = *(const half8*)(h0rd + hb);
        const half8 A2 = *(const half8*)(h0rd + hb + 32);
        const half8 A3 = *(const half8*)(h1rd + hb);
        const half8 A4 = *(const half8*)(h1rd + hb + 32);
        #pragma unroll
        for (int ti = 0; ti < 4; ++ti) {
            f32x4 acc;
            acc   = __builtin_amdgcn_mfma_f32_16x16x32_f16(A1, Bf[ti][0], biasv[ti], 0, 0, 0);
            acc   = __builtin_amdgcn_mfma_f32_16x16x32_f16(A2, Bf[ti][1], acc, 0, 0, 0);
            acc   = __builtin_amdgcn_mfma_f32_16x16x32_f16(A3, Bf[ti][2], acc, 0, 0, 0);
            g[ti] = __builtin_amdgcn_mfma_f32_16x16x32_f16(A4, Bf[ti][3], acc, 0, 0, 0);
        }
    };
    auto act_store = [&](f16* dst) {
        #pragma unroll
        for (int j = 0; j < 2; ++j) {
            const float pi = g[0][j], pf = g[1][j], pg = g[2][j], po = g[3][j];
            float& c = j ? cst1 : cst0;
            c = sig2(pf) * c + sig2(pi) * tanh2(pg);
            dst[(mrow + j) * HSTR + uu] = (f16)(sig2(po) * tanh2(c * LOG2E2));
        }
    };

    __syncthreads();

    // ---- round 0 (L0 only; h0(-1)=0) ----
    if (isL0) { l0_mfma(0, h0s[1]); act_store(h0s[0]); }
    __syncthreads();
    // ---- round 1 (L1 starts: h0(0), h1(-1)=0) ----
    if (isL0) { l0_mfma(1, h0s[0]); act_store(h0s[1]); }
    else      { l1_mfma(h0s[0], h1s[1]); act_store(h1s[0]); }
    __syncthreads();

    // ---- main rounds 2..509, parity pairs ----
    #pragma unroll 1
    for (int r = 2; r < 510; r += 2) {
        if (isL0) { l0_mfma(r, h0s[1]); act_store(h0s[0]); }
        else      { l1_mfma(h0s[1], h1s[0]); act_store(h1s[1]); }
        __syncthreads();
        if (isL0) { l0_mfma(r + 1, h0s[0]); act_store(h0s[1]); }
        else      { l1_mfma(h0s[0], h1s[1]); act_store(h1s[0]); }
        __syncthreads();
    }
    // ---- rounds 510, 511 ----
    if (isL0) { l0_mfma(510, h0s[1]); act_store(h0s[0]); }
    else      { l1_mfma(h0s[1], h1s[0]); act_store(h1s[1]); }
    __syncthreads();
    if (isL0) { l0_mfma(511, h0s[0]); act_store(h0s[1]); }
    else      { l1_mfma(h0s[0], h1s[1]); act_store(h1s[0]); }
    __syncthreads();
    // ---- round 512 (L1 drain): h1(511) -> h1s[1] ----
    if (!isL0) { l1_mfma(h0s[1], h1s[0]); act_store(h1s[1]); }
    __syncthreads();

    // ---- epilogue: out[b][v] = tanh(h1(511) . fc_w[v] + fc_b[v]) ----
    {
        const int v = tid & 63;
        const int m = tid >> 6;
        float a = fc_b[v];
        const f16* hp = h1s[1] + m * HSTR;
        const float4* wp = (const float4*)(fc_w + v * HID);
        #pragma unroll
        for (int kk = 0; kk < HID / 4; ++kk) {
            const float4 wv = wp[kk];
            a += (float)hp[kk * 4 + 0] * wv.x + (float)hp[kk * 4 + 1] * wv.y
               + (float)hp[kk * 4 + 2] * wv.z + (float)hp[kk * 4 + 3] * wv.w;
        }
        out[(size_t)(b0 + m) * HID + v] = tanh2(a * LOG2E2);
    }
}

extern "C" void kernel_launch(void* const* d_in, const int* in_sizes, int n_in,
                              void* d_out, int out_size, void* d_ws, size_t ws_size,
                              hipStream_t stream) {
    const float* x     = (const float*)d_in[0];
    const float* w_ih0 = (const float*)d_in[1];
    const float* w_hh0 = (const float*)d_in[2];
    const float* b_ih0 = (const float*)d_in[3];
    const float* b_hh0 = (const float*)d_in[4];
    const float* w_ih1 = (const float*)d_in[5];
    const float* w_hh1 = (const float*)d_in[6];
    const float* b_ih1 = (const float*)d_in[7];
    const float* b_hh1 = (const float*)d_in[8];
    const float* fc_w  = (const float*)d_in[9];
    const float* fc_b  = (const float*)d_in[10];
    float* out = (float*)d_out;

    const int B = in_sizes[0] / (TSTEPS * 4);   // 2048
    lstm_mfma<<<dim3(B / MB), dim3(BLK), 0, stream>>>(
        x, w_ih0, w_hh0, b_ih0, b_hh0, w_ih1, w_hh1, b_ih1, b_hh1, fc_w, fc_b, out);
}

// Round 9
// 330.248 us; speedup vs baseline: 1.2096x; 1.0069x over previous
//
#include <hip/hip_runtime.h>

// 2-layer LSTM (B=2048,T=512,in=4,H=64) + FC + tanh. MFMA f16, wave-specialized,
// 1 barrier/round, fused-rcp activations, software-pipelined x reads.
//
// Additive-issue model (validated R3/R6/R7/R8): round = MFMA-pipe + VALU-issue
// + barrier per SIMD. MFMA floor 490 cyc (28 MFMA/SIMD, structural). This
// round cuts the trans floor: sig(i)*tanh(g) and sig(o)*tanh(c) each share one
// rcp -> 8 trans/cell (5 exp2 + 3 rcp) vs 10. One v_min guards exp2(ec-arg)
// <= 126 so (1-inf)*0 NaN can't form. x(r+1) is prefetched from read-only xs
// before the barrier to hide the ds_write drain.
//
// Round r: L0 waves (0-3): MFMA step r [x(r), h0(r-1)@pv] -> act -> h0(r)@pr
//          L1 waves (4-7): MFMA step r-1 [h0(r-1)@pv, h1(r-2)@pr] -> act -> h1(r-1)@pv
//          one __syncthreads.

#define HID 64
#define TSTEPS 512
#define MB 8
#define BLK 512
#define HSTR 72   // f16 words per h row (144 B: 16B-aligned b128)
#define LOG2E  1.4426950408889634f
#define LOG2E2 2.8853900817779268f

typedef _Float16 f16;
typedef _Float16 half8 __attribute__((ext_vector_type(8)));
typedef _Float16 half4 __attribute__((ext_vector_type(4)));
typedef float f32x4 __attribute__((ext_vector_type(4)));

__device__ __forceinline__ float sig2(float y) {   // sigmoid(x), y = x*log2e
    return __builtin_amdgcn_rcpf(1.0f + __builtin_amdgcn_exp2f(-y));
}
__device__ __forceinline__ float tanh2(float y) {  // tanh(x), y = x*2*log2e
    return fmaf(2.0f, __builtin_amdgcn_rcpf(1.0f + __builtin_amdgcn_exp2f(-y)), -1.0f);
}

__global__ __launch_bounds__(BLK, 2) void lstm_mfma(
    const float* __restrict__ x,      // (2048, 512, 4)
    const float* __restrict__ w_ih0,  // (256, 4)
    const float* __restrict__ w_hh0,  // (256, 64)
    const float* __restrict__ b_ih0,  // (256,)
    const float* __restrict__ b_hh0,  // (256,)
    const float* __restrict__ w_ih1,  // (256, 64)
    const float* __restrict__ w_hh1,  // (256, 64)
    const float* __restrict__ b_ih1,  // (256,)
    const float* __restrict__ b_hh1,  // (256,)
    const float* __restrict__ fc_w,   // (64, 64)
    const float* __restrict__ fc_b,   // (64,)
    float* __restrict__ out)          // (2048, 64)
{
    __shared__ f16 xs[TSTEPS * MB * 4];     // 32 KB
    __shared__ f16 h0s[2][MB * HSTR];       // parity dbuf
    __shared__ f16 h1s[2][MB * HSTR];       // parity dbuf

    const int tid  = threadIdx.x;
    const int w    = tid >> 6;        // wave 0..7
    const int l    = tid & 63;
    const int quad = l >> 4;
    const int l15  = l & 15;
    const int wl   = w & 3;
    const bool isL0 = (w < 4);
    const int b0   = blockIdx.x * MB;

    // rotated duplicate-row map: rows 0-7 = batches 0-7,
    // rows 8-15 = batches {2,3,0,1,6,7,4,5} (makes act regs uniform {0,1}).
    const int RM = (l15 < 8) ? l15 : ((l15 & 4) | ((l15 + 2) & 3));

    // ---- stage x into LDS as f16 ----
    for (int it = tid; it < MB * TSTEPS; it += BLK) {
        const int m = it >> 9;
        const int t = it & 511;
        const float4 v = *((const float4*)x + (size_t)(b0 + m) * TSTEPS + t);
        *(half4*)(xs + (t * MB + m) * 4) =
            (half4){ (f16)v.x, (f16)v.y, (f16)v.z, (f16)v.w };
    }
    for (int it = tid; it < MB * HSTR; it += BLK) {
        h0s[0][it] = (f16)0.f; h0s[1][it] = (f16)0.f;
        h1s[0][it] = (f16)0.f; h1s[1][it] = (f16)0.f;
    }

    // ---- B-fragments: 4 N-tiles x up-to-4 K-chunks, prescaled by log2e ----
    // B[k=quad*8+j][n=(wl+4*ti)*16+l15]; tile ti == gate ti of units wl*16+l15.
    // L0: [0]=x-proj(pad), [1-2]=w_hh0.  L1: [0-1]=w_ih1, [2-3]=w_hh1.
    half8 Bf[4][4];
    f32x4 biasv[4];                 // persistent C-operand
    const half8 Z = { (f16)0.f,(f16)0.f,(f16)0.f,(f16)0.f,
                      (f16)0.f,(f16)0.f,(f16)0.f,(f16)0.f };
    #pragma unroll
    for (int ti = 0; ti < 4; ++ti) {
        const int n = (wl + 4 * ti) * 16 + l15;
        const float sc = (ti == 2) ? LOG2E2 : LOG2E;   // g-gate feeds tanh path
        float bval;
        if (isL0) {
            bval = (b_ih0[n] + b_hh0[n]) * sc;
            half8 pz = Z;
            if (quad == 0) {
                const float4 v = *(const float4*)(w_ih0 + n * 4);
                pz[0] = (f16)(v.x * sc); pz[1] = (f16)(v.y * sc);
                pz[2] = (f16)(v.z * sc); pz[3] = (f16)(v.w * sc);
            }
            Bf[ti][0] = pz;
            #pragma unroll
            for (int ks = 0; ks < 2; ++ks) {
                const int ko = ks * 32 + quad * 8;
                const float4 a = *(const float4*)(w_hh0 + n * HID + ko);
                const float4 b = *(const float4*)(w_hh0 + n * HID + ko + 4);
                Bf[ti][1 + ks] = (half8){
                    (f16)(a.x*sc),(f16)(a.y*sc),(f16)(a.z*sc),(f16)(a.w*sc),
                    (f16)(b.x*sc),(f16)(b.y*sc),(f16)(b.z*sc),(f16)(b.w*sc) };
            }
            Bf[ti][3] = Z;
        } else {
            bval = (b_ih1[n] + b_hh1[n]) * sc;
            #pragma unroll
            for (int ks = 0; ks < 2; ++ks) {
                const int ko = ks * 32 + quad * 8;
                const float4 a = *(const float4*)(w_ih1 + n * HID + ko);
                const float4 b = *(const float4*)(w_ih1 + n * HID + ko + 4);
                Bf[ti][ks] = (half8){
                    (f16)(a.x*sc),(f16)(a.y*sc),(f16)(a.z*sc),(f16)(a.w*sc),
                    (f16)(b.x*sc),(f16)(b.y*sc),(f16)(b.z*sc),(f16)(b.w*sc) };
                const float4 c = *(const float4*)(w_hh1 + n * HID + ko);
                const float4 d = *(const float4*)(w_hh1 + n * HID + ko + 4);
                Bf[ti][2 + ks] = (half8){
                    (f16)(c.x*sc),(f16)(c.y*sc),(f16)(c.z*sc),(f16)(c.w*sc),
                    (f16)(d.x*sc),(f16)(d.y*sc),(f16)(d.z*sc),(f16)(d.w*sc) };
            }
        }
        biasv[ti] = (f32x4){ bval, bval, bval, bval };
    }

    // act ownership: lane (quad,l15) owns C/D regs {0,1} = batches
    // {mrow, mrow+1}, unit uu.  quad 0,1,2,3 -> mrow 0,4,2,6.
    const int  mrow = (quad & 1) * 4 + (quad & 2);
    const int  uu   = wl * 16 + l15;
    const int  hb   = RM * HSTR + quad * 8;   // A-frag base (rotated rows)
    float cst0 = 0.f, cst1 = 0.f;
    f32x4 g[4];

    auto load_x = [&](int r) -> half4 {
        return *(const half4*)(xs + (r * MB + RM) * 4);
    };
    auto l0_mfma = [&](half4 xv, const f16* h0rd) {
        half8 ax = Z;
        if (quad == 0) { ax[0]=xv[0]; ax[1]=xv[1]; ax[2]=xv[2]; ax[3]=xv[3]; }
        const half8 A1 = *(const half8*)(h0rd + hb);
        const half8 A2 = *(const half8*)(h0rd + hb + 32);
        #pragma unroll
        for (int ti = 0; ti < 4; ++ti) {
            f32x4 acc;
            acc   = __builtin_amdgcn_mfma_f32_16x16x32_f16(ax, Bf[ti][0], biasv[ti], 0, 0, 0);
            acc   = __builtin_amdgcn_mfma_f32_16x16x32_f16(A1, Bf[ti][1], acc, 0, 0, 0);
            g[ti] = __builtin_amdgcn_mfma_f32_16x16x32_f16(A2, Bf[ti][2], acc, 0, 0, 0);
        }
    };
    auto l1_mfma = [&](const f16* h0rd, const f16* h1rd) {
        const half8 A1 = *(const half8*)(h0rd + hb);
        const half8 A2 = *(const half8*)(h0rd + hb + 32);
        const half8 A3 = *(const half8*)(h1rd + hb);
        const half8 A4 = *(const half8*)(h1rd + hb + 32);
        #pragma unroll
        for (int ti = 0; ti < 4; ++ti) {
            f32x4 acc;
            acc   = __builtin_amdgcn_mfma_f32_16x16x32_f16(A1, Bf[ti][0], biasv[ti], 0, 0, 0);
            acc   = __builtin_amdgcn_mfma_f32_16x16x32_f16(A2, Bf[ti][1], acc, 0, 0, 0);
            acc   = __builtin_amdgcn_mfma_f32_16x16x32_f16(A3, Bf[ti][2], acc, 0, 0, 0);
            g[ti] = __builtin_amdgcn_mfma_f32_16x16x32_f16(A4, Bf[ti][3], acc, 0, 0, 0);
        }
    };
    // fused-rcp activations: 5 exp2 + 3 rcp per cell.
    //   sig(i)*tanh(g) = (1-eg)*rcp((1+ei)(1+eg))
    //   sig(f)*c       = c*rcp(1+ef)
    //   sig(o)*tanh(c) = (1-ec)*rcp((1+eo)(1+ec)), exp2 arg clamped <=126
    auto act_store = [&](f16* dst) {
        #pragma unroll
        for (int j = 0; j < 2; ++j) {
            const float ei = __builtin_amdgcn_exp2f(-g[0][j]);
            const float ef = __builtin_amdgcn_exp2f(-g[1][j]);
            const float eg = __builtin_amdgcn_exp2f(-g[2][j]);
            const float eo = __builtin_amdgcn_exp2f(-g[3][j]);
            float& c = j ? cst1 : cst0;
            const float r0 = __builtin_amdgcn_rcpf(1.0f + ef);
            const float r1 = __builtin_amdgcn_rcpf((1.0f + ei) * (1.0f + eg));
            c = fmaf(c, r0, (1.0f - eg) * r1);
            const float ym = fminf(-LOG2E2 * c, 126.0f);
            const float ec = __builtin_amdgcn_exp2f(ym);
            const float r2 = __builtin_amdgcn_rcpf((1.0f + eo) * (1.0f + ec));
            dst[(mrow + j) * HSTR + uu] = (f16)((1.0f - ec) * r2);
        }
    };

    __syncthreads();

    half4 xv;
    if (isL0) xv = load_x(0);
    // ---- round 0 (L0 only; h0(-1)=0) ----
    if (isL0) { l0_mfma(xv, h0s[1]); act_store(h0s[0]); xv = load_x(1); }
    __syncthreads();
    // ---- round 1 (L1 starts: h0(0), h1(-1)=0) ----
    if (isL0) { l0_mfma(xv, h0s[0]); act_store(h0s[1]); xv = load_x(2); }
    else      { l1_mfma(h0s[0], h1s[1]); act_store(h1s[0]); }
    __syncthreads();

    // ---- main rounds 2..509, parity pairs; xv always holds x(r) on entry ----
    #pragma unroll 1
    for (int r = 2; r < 510; r += 2) {
        if (isL0) { l0_mfma(xv, h0s[1]); act_store(h0s[0]); xv = load_x(r + 1); }
        else      { l1_mfma(h0s[1], h1s[0]); act_store(h1s[1]); }
        __syncthreads();
        if (isL0) { l0_mfma(xv, h0s[0]); act_store(h0s[1]); xv = load_x(r + 2); }
        else      { l1_mfma(h0s[0], h1s[1]); act_store(h1s[0]); }
        __syncthreads();
    }
    // ---- rounds 510, 511 ----
    if (isL0) { l0_mfma(xv, h0s[1]); act_store(h0s[0]); xv = load_x(511); }
    else      { l1_mfma(h0s[1], h1s[0]); act_store(h1s[1]); }
    __syncthreads();
    if (isL0) { l0_mfma(xv, h0s[0]); act_store(h0s[1]); }
    else      { l1_mfma(h0s[0], h1s[1]); act_store(h1s[0]); }
    __syncthreads();
    // ---- round 512 (L1 drain): h1(511) -> h1s[1] ----
    if (!isL0) { l1_mfma(h0s[1], h1s[0]); act_store(h1s[1]); }
    __syncthreads();

    // ---- epilogue: out[b][v] = tanh(h1(511) . fc_w[v] + fc_b[v]) ----
    {
        const int v = tid & 63;
        const int m = tid >> 6;
        float a = fc_b[v];
        const f16* hp = h1s[1] + m * HSTR;
        const float4* wp = (const float4*)(fc_w + v * HID);
        #pragma unroll
        for (int kk = 0; kk < HID / 4; ++kk) {
            const float4 wv = wp[kk];
            a += (float)hp[kk * 4 + 0] * wv.x + (float)hp[kk * 4 + 1] * wv.y
               + (float)hp[kk * 4 + 2] * wv.z + (float)hp[kk * 4 + 3] * wv.w;
        }
        out[(size_t)(b0 + m) * HID + v] = tanh2(a * LOG2E2);
    }
}

extern "C" void kernel_launch(void* const* d_in, const int* in_sizes, int n_in,
                              void* d_out, int out_size, void* d_ws, size_t ws_size,
                              hipStream_t stream) {
    const float* x     = (const float*)d_in[0];
    const float* w_ih0 = (const float*)d_in[1];
    const float* w_hh0 = (const float*)d_in[2];
    const float* b_ih0 = (const float*)d_in[3];
    const float* b_hh0 = (const float*)d_in[4];
    const float* w_ih1 = (const float*)d_in[5];
    const float* w_hh1 = (const float*)d_in[6];
    const float* b_ih1 = (const float*)d_in[7];
    const float* b_hh1 = (const float*)d_in[8];
    const float* fc_w  = (const float*)d_in[9];
    const float* fc_b  = (const float*)d_in[10];
    float* out = (float*)d_out;

    const int B = in_sizes[0] / (TSTEPS * 4);   // 2048
    lstm_mfma<<<dim3(B / MB), dim3(BLK), 0, stream>>>(
        x, w_ih0, w_hh0, b_ih0, b_hh0, w_ih1, w_hh1, b_ih1, b_hh1, fc_w, fc_b, out);
}

// Round 10
// 325.661 us; speedup vs baseline: 1.2266x; 1.0141x over previous
//
#include <hip/hip_runtime.h>

// 2-layer LSTM (B=2048,T=512,in=4,H=64) + FC + tanh. MFMA f16, wave-specialized,
// 1 barrier/round. R10: common-denominator c-update (7 trans/cell, one rcp
// saved) + HSTR 88 bank-conflict experiment on the A-frag ds_read_b128s.
//
// Calibrated per-SIMD round model (R3..R9): MFMA 28x17.7=496 + trans
// (4 cells x 8 x 16cyc = 512) + cheap ~140 + barrier ~220 = 1378 cyc.
// This round: trans 8->7/cell (-48 cyc), A-frag bank-class remap (-0..99).
//
// Round r: L0 waves (0-3): MFMA step r [x(r), h0(r-1)@pv] -> act -> h0(r)@pr
//          L1 waves (4-7): MFMA step r-1 [h0(r-1)@pv, h1(r-2)@pr] -> act -> h1(r-1)@pv
//          one __syncthreads.
// Safety: gate preacts bounded (|W|<=0.125,|h|<=1 -> |pre|<9 -> e in 2^±13,
// all CD products finite). Only exp2(c-path) needs the fmin guard.

#define HID 64
#define TSTEPS 512
#define MB 8
#define BLK 512
#define HSTR 88   // f16 words per h row; 176 B: 16B-aligned b128, stride 44 dw
                  // == 12 mod 32 banks (R9's 72 -> 4 mod 32 measured 4-way)
#define LOG2E  1.4426950408889634f
#define LOG2E2 2.8853900817779268f

typedef _Float16 f16;
typedef _Float16 half8 __attribute__((ext_vector_type(8)));
typedef _Float16 half4 __attribute__((ext_vector_type(4)));
typedef float f32x4 __attribute__((ext_vector_type(4)));

__device__ __forceinline__ float tanh2(float y) {  // tanh(x), y = x*2*log2e
    return fmaf(2.0f, __builtin_amdgcn_rcpf(1.0f + __builtin_amdgcn_exp2f(-y)), -1.0f);
}

__global__ __launch_bounds__(BLK, 2) void lstm_mfma(
    const float* __restrict__ x,      // (2048, 512, 4)
    const float* __restrict__ w_ih0,  // (256, 4)
    const float* __restrict__ w_hh0,  // (256, 64)
    const float* __restrict__ b_ih0,  // (256,)
    const float* __restrict__ b_hh0,  // (256,)
    const float* __restrict__ w_ih1,  // (256, 64)
    const float* __restrict__ w_hh1,  // (256, 64)
    const float* __restrict__ b_ih1,  // (256,)
    const float* __restrict__ b_hh1,  // (256,)
    const float* __restrict__ fc_w,   // (64, 64)
    const float* __restrict__ fc_b,   // (64,)
    float* __restrict__ out)          // (2048, 64)
{
    __shared__ f16 xs[TSTEPS * MB * 4];     // 32 KB
    __shared__ f16 h0s[2][MB * HSTR];       // parity dbuf
    __shared__ f16 h1s[2][MB * HSTR];       // parity dbuf

    const int tid  = threadIdx.x;
    const int w    = tid >> 6;        // wave 0..7
    const int l    = tid & 63;
    const int quad = l >> 4;
    const int l15  = l & 15;
    const int wl   = w & 3;
    const bool isL0 = (w < 4);
    const int b0   = blockIdx.x * MB;

    // rotated duplicate-row map: rows 0-7 = batches 0-7,
    // rows 8-15 = batches {2,3,0,1,6,7,4,5} (act regs uniform {0,1}).
    const int RM = (l15 < 8) ? l15 : ((l15 & 4) | ((l15 + 2) & 3));

    // ---- stage x into LDS as f16 ----
    for (int it = tid; it < MB * TSTEPS; it += BLK) {
        const int m = it >> 9;
        const int t = it & 511;
        const float4 v = *((const float4*)x + (size_t)(b0 + m) * TSTEPS + t);
        *(half4*)(xs + (t * MB + m) * 4) =
            (half4){ (f16)v.x, (f16)v.y, (f16)v.z, (f16)v.w };
    }
    for (int it = tid; it < MB * HSTR; it += BLK) {
        h0s[0][it] = (f16)0.f; h0s[1][it] = (f16)0.f;
        h1s[0][it] = (f16)0.f; h1s[1][it] = (f16)0.f;
    }

    // ---- B-fragments: 4 N-tiles x up-to-4 K-chunks, prescaled by log2e ----
    // B[k=quad*8+j][n=(wl+4*ti)*16+l15]; tile ti == gate ti of units wl*16+l15.
    // L0: [0]=x-proj(pad), [1-2]=w_hh0.  L1: [0-1]=w_ih1, [2-3]=w_hh1.
    half8 Bf[4][4];
    f32x4 biasv[4];                 // persistent C-operand
    const half8 Z = { (f16)0.f,(f16)0.f,(f16)0.f,(f16)0.f,
                      (f16)0.f,(f16)0.f,(f16)0.f,(f16)0.f };
    #pragma unroll
    for (int ti = 0; ti < 4; ++ti) {
        const int n = (wl + 4 * ti) * 16 + l15;
        const float sc = (ti == 2) ? LOG2E2 : LOG2E;   // g-gate feeds tanh path
        float bval;
        if (isL0) {
            bval = (b_ih0[n] + b_hh0[n]) * sc;
            half8 pz = Z;
            if (quad == 0) {
                const float4 v = *(const float4*)(w_ih0 + n * 4);
                pz[0] = (f16)(v.x * sc); pz[1] = (f16)(v.y * sc);
                pz[2] = (f16)(v.z * sc); pz[3] = (f16)(v.w * sc);
            }
            Bf[ti][0] = pz;
            #pragma unroll
            for (int ks = 0; ks < 2; ++ks) {
                const int ko = ks * 32 + quad * 8;
                const float4 a = *(const float4*)(w_hh0 + n * HID + ko);
                const float4 b = *(const float4*)(w_hh0 + n * HID + ko + 4);
                Bf[ti][1 + ks] = (half8){
                    (f16)(a.x*sc),(f16)(a.y*sc),(f16)(a.z*sc),(f16)(a.w*sc),
                    (f16)(b.x*sc),(f16)(b.y*sc),(f16)(b.z*sc),(f16)(b.w*sc) };
            }
            Bf[ti][3] = Z;
        } else {
            bval = (b_ih1[n] + b_hh1[n]) * sc;
            #pragma unroll
            for (int ks = 0; ks < 2; ++ks) {
                const int ko = ks * 32 + quad * 8;
                const float4 a = *(const float4*)(w_ih1 + n * HID + ko);
                const float4 b = *(const float4*)(w_ih1 + n * HID + ko + 4);
                Bf[ti][ks] = (half8){
                    (f16)(a.x*sc),(f16)(a.y*sc),(f16)(a.z*sc),(f16)(a.w*sc),
                    (f16)(b.x*sc),(f16)(b.y*sc),(f16)(b.z*sc),(f16)(b.w*sc) };
                const float4 c = *(const float4*)(w_hh1 + n * HID + ko);
                const float4 d = *(const float4*)(w_hh1 + n * HID + ko + 4);
                Bf[ti][2 + ks] = (half8){
                    (f16)(c.x*sc),(f16)(c.y*sc),(f16)(c.z*sc),(f16)(c.w*sc),
                    (f16)(d.x*sc),(f16)(d.y*sc),(f16)(d.z*sc),(f16)(d.w*sc) };
            }
        }
        biasv[ti] = (f32x4){ bval, bval, bval, bval };
    }

    // act ownership: lane (quad,l15) owns C/D regs {0,1} = batches
    // {mrow, mrow+1}, unit uu.  quad 0,1,2,3 -> mrow 0,4,2,6.
    const int  mrow = (quad & 1) * 4 + (quad & 2);
    const int  uu   = wl * 16 + l15;
    const int  hb   = RM * HSTR + quad * 8;   // A-frag base (rotated rows)
    float cst0 = 0.f, cst1 = 0.f;
    f32x4 g[4];

    auto load_x = [&](int r) -> half4 {
        return *(const half4*)(xs + (r * MB + RM) * 4);
    };
    auto l0_mfma = [&](half4 xv, const f16* h0rd) {
        half8 ax = Z;
        if (quad == 0) { ax[0]=xv[0]; ax[1]=xv[1]; ax[2]=xv[2]; ax[3]=xv[3]; }
        const half8 A1 = *(const half8*)(h0rd + hb);
        const half8 A2 = *(const half8*)(h0rd + hb + 32);
        #pragma unroll
        for (int ti = 0; ti < 4; ++ti) {
            f32x4 acc;
            acc   = __builtin_amdgcn_mfma_f32_16x16x32_f16(ax, Bf[ti][0], biasv[ti], 0, 0, 0);
            acc   = __builtin_amdgcn_mfma_f32_16x16x32_f16(A1, Bf[ti][1], acc, 0, 0, 0);
            g[ti] = __builtin_amdgcn_mfma_f32_16x16x32_f16(A2, Bf[ti][2], acc, 0, 0, 0);
        }
    };
    auto l1_mfma = [&](const f16* h0rd, const f16* h1rd) {
        const half8 A1 = *(const half8*)(h0rd + hb);
        const half8 A2 = *(const half8*)(h0rd + hb + 32);
        const half8 A3 = *(const half8*)(h1rd + hb);
        const half8 A4 = *(const half8*)(h1rd + hb + 32);
        #pragma unroll
        for (int ti = 0; ti < 4; ++ti) {
            f32x4 acc;
            acc   = __builtin_amdgcn_mfma_f32_16x16x32_f16(A1, Bf[ti][0], biasv[ti], 0, 0, 0);
            acc   = __builtin_amdgcn_mfma_f32_16x16x32_f16(A2, Bf[ti][1], acc, 0, 0, 0);
            acc   = __builtin_amdgcn_mfma_f32_16x16x32_f16(A3, Bf[ti][2], acc, 0, 0, 0);
            g[ti] = __builtin_amdgcn_mfma_f32_16x16x32_f16(A4, Bf[ti][3], acc, 0, 0, 0);
        }
    };
    // activations, 7 trans/cell (5 exp2 + 2 rcp):
    //   common denominator: c' = [c*(1+ei)(1+eg) + (1-eg)(1+ef)]
    //                           * rcp((1+ef)(1+ei)(1+eg))
    //   h = (1-ec)*rcp((1+eo)(1+ec)),  exp2 arg of ec clamped <= 126
    auto act_store = [&](f16* dst) {
        #pragma unroll
        for (int j = 0; j < 2; ++j) {
            const float ei = __builtin_amdgcn_exp2f(-g[0][j]);
            const float ef = __builtin_amdgcn_exp2f(-g[1][j]);
            const float eg = __builtin_amdgcn_exp2f(-g[2][j]);
            const float eo = __builtin_amdgcn_exp2f(-g[3][j]);
            float& c = j ? cst1 : cst0;
            const float af = 1.0f + ef;
            const float P  = (1.0f + ei) * (1.0f + eg);
            const float N  = fmaf(c * P, 1.0f, (1.0f - eg) * af);  // c*P + (1-eg)*af
            c = N * __builtin_amdgcn_rcpf(P * af);
            const float ym = fminf(-LOG2E2 * c, 126.0f);
            const float ec = __builtin_amdgcn_exp2f(ym);
            const float r2 = __builtin_amdgcn_rcpf((1.0f + eo) * (1.0f + ec));
            dst[(mrow + j) * HSTR + uu] = (f16)((1.0f - ec) * r2);
        }
    };

    __syncthreads();

    half4 xv;
    if (isL0) xv = load_x(0);
    // ---- round 0 (L0 only; h0(-1)=0) ----
    if (isL0) { l0_mfma(xv, h0s[1]); act_store(h0s[0]); xv = load_x(1); }
    __syncthreads();
    // ---- round 1 (L1 starts: h0(0), h1(-1)=0) ----
    if (isL0) { l0_mfma(xv, h0s[0]); act_store(h0s[1]); xv = load_x(2); }
    else      { l1_mfma(h0s[0], h1s[1]); act_store(h1s[0]); }
    __syncthreads();

    // ---- main rounds 2..509, parity pairs; xv holds x(r) on entry ----
    #pragma unroll 1
    for (int r = 2; r < 510; r += 2) {
        if (isL0) { l0_mfma(xv, h0s[1]); act_store(h0s[0]); xv = load_x(r + 1); }
        else      { l1_mfma(h0s[1], h1s[0]); act_store(h1s[1]); }
        __syncthreads();
        if (isL0) { l0_mfma(xv, h0s[0]); act_store(h0s[1]); xv = load_x(r + 2); }
        else      { l1_mfma(h0s[0], h1s[1]); act_store(h1s[0]); }
        __syncthreads();
    }
    // ---- rounds 510, 511 ----
    if (isL0) { l0_mfma(xv, h0s[1]); act_store(h0s[0]); xv = load_x(511); }
    else      { l1_mfma(h0s[1], h1s[0]); act_store(h1s[1]); }
    __syncthreads();
    if (isL0) { l0_mfma(xv, h0s[0]); act_store(h0s[1]); }
    else      { l1_mfma(h0s[0], h1s[1]); act_store(h1s[0]); }
    __syncthreads();
    // ---- round 512 (L1 drain): h1(511) -> h1s[1] ----
    if (!isL0) { l1_mfma(h0s[1], h1s[0]); act_store(h1s[1]); }
    __syncthreads();

    // ---- epilogue: out[b][v] = tanh(h1(511) . fc_w[v] + fc_b[v]) ----
    {
        const int v = tid & 63;
        const int m = tid >> 6;
        float a = fc_b[v];
        const f16* hp = h1s[1] + m * HSTR;
        const float4* wp = (const float4*)(fc_w + v * HID);
        #pragma unroll
        for (int kk = 0; kk < HID / 4; ++kk) {
            const float4 wv = wp[kk];
            a += (float)hp[kk * 4 + 0] * wv.x + (float)hp[kk * 4 + 1] * wv.y
               + (float)hp[kk * 4 + 2] * wv.z + (float)hp[kk * 4 + 3] * wv.w;
        }
        out[(size_t)(b0 + m) * HID + v] = tanh2(a * LOG2E2);
    }
}

extern "C" void kernel_launch(void* const* d_in, const int* in_sizes, int n_in,
                              void* d_out, int out_size, void* d_ws, size_t ws_size,
                              hipStream_t stream) {
    const float* x     = (const float*)d_in[0];
    const float* w_ih0 = (const float*)d_in[1];
    const float* w_hh0 = (const float*)d_in[2];
    const float* b_ih0 = (const float*)d_in[3];
    const float* b_hh0 = (const float*)d_in[4];
    const float* w_ih1 = (const float*)d_in[5];
    const float* w_hh1 = (const float*)d_in[6];
    const float* b_ih1 = (const float*)d_in[7];
    const float* b_hh1 = (const float*)d_in[8];
    const float* fc_w  = (const float*)d_in[9];
    const float* fc_b  = (const float*)d_in[10];
    float* out = (float*)d_out;

    const int B = in_sizes[0] / (TSTEPS * 4);   // 2048
    lstm_mfma<<<dim3(B / MB), dim3(BLK), 0, stream>>>(
        x, w_ih0, w_hh0, b_ih0, b_hh0, w_ih1, w_hh1, b_ih1, b_hh1, fc_w, fc_b, out);
}